// Round 9
// baseline (461.811 us; speedup 1.0000x reference)
//
#include <hip/hip_runtime.h>
#include <stdint.h>

// Self-attention, SEQ=8192, D=768, single head.
//   K0a: x fp32->bf16; K0b: Wq/Wk/Wv fp32->bf16 (z-fused)
//   K1a: Q,K projections z-fused (MODE 0); K1b: Vt = Wv x^T (MODE 0)
//   K2 : P' = exp(Q K^T) bf16 + atomic row sums (MODE 1)
//   K3 : out += (P'_chunk V)/rowsum, split-K x4, fp32 atomicAdd (MODE 2)
// R4: XCD swizzle -> FETCH at unique floor. R5: BK=64, conflicts 0, 433us.
// R6: dbuf via global_load_lds NEUTRAL. R7: LDS-free regressed (no compiler
//     pipelining). R8: 32x32x16 MFMA + 4blk/CU -> 420us, but (a) conflicts
//     back (1.26e7 = 4cyc x 3.15M b128) and (b) ~84% of wave time is the
//     barrier drain: global_load_lds's dest IS LDS, so vmcnt(0)-before-barrier
//     must drain staging -> loads can never stay in flight across the barrier.
// R9: AITER-style REGISTER staging: global->VGPR (buffer_load) -> ds_write ->
//     barrier. vmcnt wait attaches to ds_write (covered by a full compute
//     phase); at the barrier zero VMEM outstanding -> drain is free. Register
//     staging drops the lane-linear LDS constraint -> padded stride 72
//     halfwords (144B, 16B aligned): reads AND writes at exact bank floor.

#define SEQ    8192
#define DMODEL 768
#define KSPLIT 4
#define LSTR   72            // LDS row stride in halfwords (144 B = 9*16)

typedef short bf16x8 __attribute__((ext_vector_type(8)));
typedef float f32x4  __attribute__((ext_vector_type(4)));
typedef float f32x16 __attribute__((ext_vector_type(16)));

__device__ __forceinline__ unsigned short f2bf(float f) {
  union { float f; unsigned int u; } v; v.f = f;
  unsigned int u = v.u;
  u += 0x7FFFu + ((u >> 16) & 1u);   // round-to-nearest-even
  return (unsigned short)(u >> 16);
}

__global__ void convert_x(const float* __restrict__ src,
                          unsigned short* __restrict__ dst, int n4) {
  int i = blockIdx.x * blockDim.x + threadIdx.x;
  if (i >= n4) return;
  const float4 f = ((const float4*)src)[i];
  ushort4 o;
  o.x = f2bf(f.x); o.y = f2bf(f.y); o.z = f2bf(f.z); o.w = f2bf(f.w);
  ((ushort4*)dst)[i] = o;
}

__global__ void convert_w(const float* __restrict__ s0, const float* __restrict__ s1,
                          const float* __restrict__ s2,
                          unsigned short* __restrict__ d0, unsigned short* __restrict__ d1,
                          unsigned short* __restrict__ d2, int n4) {
  const float* s = (blockIdx.z == 0) ? s0 : (blockIdx.z == 1) ? s1 : s2;
  unsigned short* d = (blockIdx.z == 0) ? d0 : (blockIdx.z == 1) ? d1 : d2;
  int i = blockIdx.x * blockDim.x + threadIdx.x;
  if (i >= n4) return;
  const float4 f = ((const float4*)s)[i];
  ushort4 o;
  o.x = f2bf(f.x); o.y = f2bf(f.y); o.z = f2bf(f.z); o.w = f2bf(f.w);
  ((ushort4*)d)[i] = o;
}

// C[m,n] = sum_k A[m,k]*B[n,k]  (A:[M,K], B:[N,K] bf16 row-major)
// GRID: blockIdx.x = M-tile, blockIdx.y = N-tile (same-A blocks -> same XCD)
// BK=64, double-buffered LDS [128][LSTR=72] (plain layout, pad kills
// conflicts). Pipeline per kt: compute(buf cur) -> ds_write(buf nxt) from regs
// loaded one iter ago (vmcnt wait covered by compute) -> barrier (lgkm only,
// no outstanding vmem) -> issue loads kt+2 -> regs.
// MFMA 32x32x16: wave quadrant 64x64 = 2x2 tiles; A-op row=lane&31,
// k=(lane>>5)*8+j; C/D col=lane&31, row=(reg&3)+8*(reg>>2)+4*(lane>>5).
// MODE 0: bf16 C*alpha; z=1 uses B2/Cout2/alpha2 (QK fusion)
// MODE 1: bf16 exp(C) + atomicAdd per-row exp-sums into rowsum
// MODE 2: split-K over z (kChunk each); atomicAdd fp32 C/rowsum[m] into Cout
template <int MODE>
__launch_bounds__(256, 2)
__global__ void gemm_bt(const unsigned short* __restrict__ A,
                        const unsigned short* __restrict__ B,
                        void* __restrict__ Cout,
                        int M, int N, int K, float alpha,
                        float* __restrict__ rowsum, int kChunk,
                        const unsigned short* __restrict__ B2,
                        void* __restrict__ Cout2, float alpha2) {
  __shared__ __align__(16) unsigned short lA[2][128 * LSTR];
  __shared__ __align__(16) unsigned short lB[2][128 * LSTR];

  if (MODE == 0) {
    if (blockIdx.z == 1) { B = B2; Cout = Cout2; alpha = alpha2; }
  }
  const int kOff = (MODE == 2) ? blockIdx.z * kChunk : 0;

  const int t    = threadIdx.x;
  const int w    = t >> 6;
  const int l    = t & 63;
  const int r32  = l & 31;     // row within a 32-tile / output col
  const int kh   = l >> 5;     // k-half selector
  const int m0   = blockIdx.x * 128;
  const int n0   = blockIdx.y * 128;
  const int wm   = (w & 1) * 64;
  const int wn   = (w >> 1) * 64;

  // Staging map: 1024 16B-chunks per tensor, 4/thread. c = t + h*256:
  // row = c>>3, k-chunk j = c&7. LDS halfword idx = row*LSTR + j*8.
  const unsigned short* sA[4];
  const unsigned short* sB[4];
  int dOff[4];
#pragma unroll
  for (int h = 0; h < 4; ++h) {
    int c   = t + (h << 8);
    int row = c >> 3;
    int j   = c & 7;
    sA[h]   = A + (size_t)(m0 + row) * K + kOff + j * 8;
    sB[h]   = B + (size_t)(n0 + row) * K + kOff + j * 8;
    dOff[h] = row * LSTR + j * 8;
  }

  f32x16 acc[2][2] = {};
  const int nk = kChunk >> 6;

  bf16x8 rA[4], rB[4];
  // Preload tile 0 -> regs -> LDS buf 0
#pragma unroll
  for (int h = 0; h < 4; ++h) { rA[h] = *(const bf16x8*)sA[h]; rB[h] = *(const bf16x8*)sB[h]; }
#pragma unroll
  for (int h = 0; h < 4; ++h) {
    *(bf16x8*)&lA[0][dOff[h]] = rA[h];
    *(bf16x8*)&lB[0][dOff[h]] = rB[h];
  }
  __syncthreads();                    // no vmem outstanding here
  if (nk > 1) {
#pragma unroll
    for (int h = 0; h < 4; ++h) { rA[h] = *(const bf16x8*)(sA[h] + 64); rB[h] = *(const bf16x8*)(sB[h] + 64); }
  }

  for (int kt = 0; kt < nk; ++kt) {
    const int cur = kt & 1;
    // Compute on buf cur while regs (tile kt+1) loads are in flight.
#pragma unroll
    for (int ks = 0; ks < 4; ++ks) {
      const int g = (ks << 1) | kh;          // 16B k-chunk 0..7
      bf16x8 aT[2], bT[2];
      aT[0] = *(const bf16x8*)&lA[cur][(wm +      r32) * LSTR + (g << 3)];
      aT[1] = *(const bf16x8*)&lA[cur][(wm + 32 + r32) * LSTR + (g << 3)];
      bT[0] = *(const bf16x8*)&lB[cur][(wn +      r32) * LSTR + (g << 3)];
      bT[1] = *(const bf16x8*)&lB[cur][(wn + 32 + r32) * LSTR + (g << 3)];
      acc[0][0] = __builtin_amdgcn_mfma_f32_32x32x16_bf16(aT[0], bT[0], acc[0][0], 0, 0, 0);
      acc[0][1] = __builtin_amdgcn_mfma_f32_32x32x16_bf16(aT[0], bT[1], acc[0][1], 0, 0, 0);
      acc[1][0] = __builtin_amdgcn_mfma_f32_32x32x16_bf16(aT[1], bT[0], acc[1][0], 0, 0, 0);
      acc[1][1] = __builtin_amdgcn_mfma_f32_32x32x16_bf16(aT[1], bT[1], acc[1][1], 0, 0, 0);
    }
    if (kt + 1 < nk) {
      const int nxt = cur ^ 1;
      // vmcnt waits live here (covered by the compute phase above)
#pragma unroll
      for (int h = 0; h < 4; ++h) {
        *(bf16x8*)&lA[nxt][dOff[h]] = rA[h];
        *(bf16x8*)&lB[nxt][dOff[h]] = rB[h];
      }
      __syncthreads();                // lgkm-only; vmem queue is empty
      if (kt + 2 < nk) {
        const int ko = (kt + 2) << 6;
#pragma unroll
        for (int h = 0; h < 4; ++h) {
          rA[h] = *(const bf16x8*)(sA[h] + ko);
          rB[h] = *(const bf16x8*)(sB[h] + ko);
        }
      }
    }
  }

  // C/D 32x32 (m74/m101): col = lane&31, row = (reg&3) + 8*(reg>>2) + 4*kh
  if (MODE == 0) {
    unsigned short* C = (unsigned short*)Cout;
#pragma unroll
    for (int mi = 0; mi < 2; ++mi)
#pragma unroll
      for (int reg = 0; reg < 16; ++reg) {
        int m = m0 + wm + mi * 32 + (reg & 3) + ((reg >> 2) << 3) + (kh << 2);
#pragma unroll
        for (int ni = 0; ni < 2; ++ni) {
          int n = n0 + wn + ni * 32 + r32;
          C[(size_t)m * N + n] = f2bf(acc[mi][ni][reg] * alpha);
        }
      }
  } else if (MODE == 1) {
    unsigned short* C = (unsigned short*)Cout;
#pragma unroll
    for (int mi = 0; mi < 2; ++mi)
#pragma unroll
      for (int reg = 0; reg < 16; ++reg) {
        int m = m0 + wm + mi * 32 + (reg & 3) + ((reg >> 2) << 3) + (kh << 2);
        float s = 0.f;
#pragma unroll
        for (int ni = 0; ni < 2; ++ni) {
          int n = n0 + wn + ni * 32 + r32;
          float p = __expf(acc[mi][ni][reg]);
          C[(size_t)m * N + n] = f2bf(p);
          s += p;
        }
        // reduce over the 32 lanes (r32) sharing this row
#pragma unroll
        for (int off = 1; off < 32; off <<= 1) s += __shfl_xor(s, off, 64);
        if (r32 == 0) atomicAdd(&rowsum[m], s);
      }
  } else {
    float* C = (float*)Cout;   // d_out fp32, zero-initialized; split-K partials
#pragma unroll
    for (int mi = 0; mi < 2; ++mi)
#pragma unroll
      for (int reg = 0; reg < 16; ++reg) {
        int m = m0 + wm + mi * 32 + (reg & 3) + ((reg >> 2) << 3) + (kh << 2);
        float inv = 1.0f / rowsum[m];
#pragma unroll
        for (int ni = 0; ni < 2; ++ni) {
          int n = n0 + wn + ni * 32 + r32;
          atomicAdd(&C[(size_t)m * N + n], acc[mi][ni][reg] * inv);
        }
      }
  }
}

extern "C" void kernel_launch(void* const* d_in, const int* in_sizes, int n_in,
                              void* d_out, int out_size, void* d_ws, size_t ws_size,
                              hipStream_t stream) {
  const float* x  = (const float*)d_in[0];
  const float* Wq = (const float*)d_in[1];
  const float* Wk = (const float*)d_in[2];
  const float* Wv = (const float*)d_in[3];

  char* ws = (char*)d_ws;
  unsigned short* xb     = (unsigned short*)(ws + 0);
  unsigned short* Qb     = (unsigned short*)(ws + 12582912);
  unsigned short* Kb     = (unsigned short*)(ws + 25165824);
  unsigned short* Vtb    = (unsigned short*)(ws + 37748736);
  unsigned short* wqb    = (unsigned short*)(ws + 50331648);
  unsigned short* wkb    = (unsigned short*)(ws + 51511296);
  unsigned short* wvb    = (unsigned short*)(ws + 52690944);
  float*          rowsum = (float*)(ws + 53870592);
  unsigned short* Pb     = (unsigned short*)(ws + 53903360);
  const size_t need = 53903360u + (size_t)SEQ * SEQ * 2u;
  if (ws_size < need) return;

  hipMemsetAsync(rowsum, 0, SEQ * sizeof(float), stream);
  hipMemsetAsync(d_out, 0, (size_t)out_size * sizeof(float), stream);

  convert_x<<<SEQ * DMODEL / 1024, 256, 0, stream>>>(x, xb, SEQ * DMODEL / 4);
  convert_w<<<dim3(DMODEL * DMODEL / 1024, 1, 3), 256, 0, stream>>>(
      Wq, Wk, Wv, wqb, wkb, wvb, DMODEL * DMODEL / 4);

  const float alpha_q = 0.03608439182435161f;  // 1/sqrt(768)
  dim3 blk(256);
  // grid.x = M-tiles, grid.y = N-tiles (XCD L2 locality)
  gemm_bt<0><<<dim3(SEQ / 128, DMODEL / 128, 2), blk, 0, stream>>>(
      xb, wqb, Qb, SEQ, DMODEL, DMODEL, alpha_q, nullptr, DMODEL,
      wkb, Kb, 1.0f);
  gemm_bt<0><<<dim3(DMODEL / 128, SEQ / 128, 1), blk, 0, stream>>>(
      wvb, xb, Vtb, DMODEL, SEQ, DMODEL, 1.0f, nullptr, DMODEL,
      nullptr, nullptr, 1.0f);
  gemm_bt<1><<<dim3(SEQ / 128, SEQ / 128, 1), blk, 0, stream>>>(
      Qb, Kb, Pb, SEQ, SEQ, DMODEL, 1.0f, rowsum, DMODEL,
      nullptr, nullptr, 1.0f);
  gemm_bt<2><<<dim3(SEQ / 128, DMODEL / 128, KSPLIT), blk, 0, stream>>>(
      Pb, Vtb, d_out, SEQ, DMODEL, SEQ, 1.0f, rowsum, SEQ / KSPLIT,
      nullptr, nullptr, 1.0f);
}

// Round 10
// 412.676 us; speedup vs baseline: 1.1191x; 1.1191x over previous
//
#include <hip/hip_runtime.h>
#include <stdint.h>

// Self-attention, SEQ=8192, D=768, single head.
//   K0a: x fp32->bf16; K0b: Wq/Wk/Wv fp32->bf16 (z-fused)
//   K1a: Q,K projections z-fused (MODE 0); K1b: Vt = Wv x^T (MODE 0)
//   K2 : P' = exp(Q K^T) bf16 + atomic row sums (MODE 1)
//   K3 : out += (P'_chunk V)/rowsum, split-K x4, fp32 atomicAdd (MODE 2)
// Measured factor ranking (R8 vs R9): occupancy > barrier-drain ~ conflicts.
//   R8 (global_load_lds, conflicts 1.26e7, vmcnt(0) drain, 3.2 blk/CU): 420us.
//   R9 (reg-staged dbuf, 0 conflicts, lgkm-only barriers, 2 blk/CU): 462us.
// R10 = best value of every variable at once: SINGLE-buffer padded LDS
//   (36KB -> 4 blk/CU) + register staging (vmcnt covered by compute; both
//   barriers lgkm-only) + stride-72 padding (0 conflicts, R9-measured) +
//   __launch_bounds__(256,4).

#define SEQ    8192
#define DMODEL 768
#define KSPLIT 4
#define LSTR   72            // LDS row stride in halfwords (144 B = 9*16B)

typedef short bf16x8 __attribute__((ext_vector_type(8)));
typedef float f32x4  __attribute__((ext_vector_type(4)));
typedef float f32x16 __attribute__((ext_vector_type(16)));

__device__ __forceinline__ unsigned short f2bf(float f) {
  union { float f; unsigned int u; } v; v.f = f;
  unsigned int u = v.u;
  u += 0x7FFFu + ((u >> 16) & 1u);   // round-to-nearest-even
  return (unsigned short)(u >> 16);
}

__global__ void convert_x(const float* __restrict__ src,
                          unsigned short* __restrict__ dst, int n4) {
  int i = blockIdx.x * blockDim.x + threadIdx.x;
  if (i >= n4) return;
  const float4 f = ((const float4*)src)[i];
  ushort4 o;
  o.x = f2bf(f.x); o.y = f2bf(f.y); o.z = f2bf(f.z); o.w = f2bf(f.w);
  ((ushort4*)dst)[i] = o;
}

__global__ void convert_w(const float* __restrict__ s0, const float* __restrict__ s1,
                          const float* __restrict__ s2,
                          unsigned short* __restrict__ d0, unsigned short* __restrict__ d1,
                          unsigned short* __restrict__ d2, int n4) {
  const float* s = (blockIdx.z == 0) ? s0 : (blockIdx.z == 1) ? s1 : s2;
  unsigned short* d = (blockIdx.z == 0) ? d0 : (blockIdx.z == 1) ? d1 : d2;
  int i = blockIdx.x * blockDim.x + threadIdx.x;
  if (i >= n4) return;
  const float4 f = ((const float4*)s)[i];
  ushort4 o;
  o.x = f2bf(f.x); o.y = f2bf(f.y); o.z = f2bf(f.z); o.w = f2bf(f.w);
  ((ushort4*)d)[i] = o;
}

// C[m,n] = sum_k A[m,k]*B[n,k]  (A:[M,K], B:[N,K] bf16 row-major)
// GRID: blockIdx.x = M-tile, blockIdx.y = N-tile (same-A blocks -> same XCD)
// BK=64, SINGLE-buffer LDS [128][LSTR=72] (padding: 0 conflicts, R9-measured).
// Register staging pipeline per kt:
//   (loads for kt+1 already in flight) compute(kt) -> barrier#1 (reads done,
//   lgkm-only) -> ds_write regs kt+1 (vmcnt wait lands here, covered by the
//   compute phase) -> barrier#2 (writes visible, lgkm-only) -> issue loads
//   kt+2 -> next iter. No vmcnt(0)-at-barrier drain anywhere.
// MFMA 32x32x16: wave quadrant 64x64 = 2x2 tiles; A-op row=lane&31,
// k=(lane>>5)*8+j; C/D col=lane&31, row=(reg&3)+8*(reg>>2)+4*(lane>>5)
// [m74/m101 HW-verified].
// MODE 0: bf16 C*alpha; z=1 uses B2/Cout2/alpha2 (QK fusion)
// MODE 1: bf16 exp(C) + atomicAdd per-row exp-sums into rowsum
// MODE 2: split-K over z (kChunk each); atomicAdd fp32 C/rowsum[m] into Cout
template <int MODE>
__launch_bounds__(256, 4)
__global__ void gemm_bt(const unsigned short* __restrict__ A,
                        const unsigned short* __restrict__ B,
                        void* __restrict__ Cout,
                        int M, int N, int K, float alpha,
                        float* __restrict__ rowsum, int kChunk,
                        const unsigned short* __restrict__ B2,
                        void* __restrict__ Cout2, float alpha2) {
  __shared__ __align__(16) unsigned short lA[128 * LSTR];
  __shared__ __align__(16) unsigned short lB[128 * LSTR];

  if (MODE == 0) {
    if (blockIdx.z == 1) { B = B2; Cout = Cout2; alpha = alpha2; }
  }
  const int kOff = (MODE == 2) ? blockIdx.z * kChunk : 0;

  const int t    = threadIdx.x;
  const int w    = t >> 6;
  const int l    = t & 63;
  const int r32  = l & 31;     // row within a 32-tile / output col
  const int kh   = l >> 5;     // k-half selector
  const int m0   = blockIdx.x * 128;
  const int n0   = blockIdx.y * 128;
  const int wm   = (w & 1) * 64;
  const int wn   = (w >> 1) * 64;

  // Staging map: 1024 16B-chunks per tensor, 4/thread. c = t + h*256:
  // row = c>>3, k-chunk j = c&7. Global offset (elements) fits in 32-bit.
  int gOff[4], dOff[4];
#pragma unroll
  for (int h = 0; h < 4; ++h) {
    int c   = t + (h << 8);
    int row = c >> 3;
    int j   = c & 7;
    gOff[h] = row * K + j * 8;          // + m0*K / n0*K folded into base ptrs
    dOff[h] = row * LSTR + j * 8;
  }
  const unsigned short* Abase = A + (size_t)m0 * K + kOff;
  const unsigned short* Bbase = B + (size_t)n0 * K + kOff;

  f32x16 acc[2][2] = {};
  const int nk = kChunk >> 6;

  bf16x8 rA[4], rB[4];
  // Preload tile 0 -> regs -> LDS; then start loads for tile 1.
#pragma unroll
  for (int h = 0; h < 4; ++h) {
    rA[h] = *(const bf16x8*)(Abase + gOff[h]);
    rB[h] = *(const bf16x8*)(Bbase + gOff[h]);
  }
#pragma unroll
  for (int h = 0; h < 4; ++h) {
    *(bf16x8*)&lA[dOff[h]] = rA[h];
    *(bf16x8*)&lB[dOff[h]] = rB[h];
  }
  __syncthreads();                      // lgkm-only (vmem already consumed)
  if (nk > 1) {
#pragma unroll
    for (int h = 0; h < 4; ++h) {
      rA[h] = *(const bf16x8*)(Abase + gOff[h] + 64);
      rB[h] = *(const bf16x8*)(Bbase + gOff[h] + 64);
    }
  }

  for (int kt = 0; kt < nk; ++kt) {
    // Compute on the single buffer; loads for kt+1 are in flight.
#pragma unroll
    for (int ks = 0; ks < 4; ++ks) {
      const int g = (ks << 1) | kh;     // 16B k-chunk 0..7
      bf16x8 aT[2], bT[2];
      aT[0] = *(const bf16x8*)&lA[(wm +      r32) * LSTR + (g << 3)];
      aT[1] = *(const bf16x8*)&lA[(wm + 32 + r32) * LSTR + (g << 3)];
      bT[0] = *(const bf16x8*)&lB[(wn +      r32) * LSTR + (g << 3)];
      bT[1] = *(const bf16x8*)&lB[(wn + 32 + r32) * LSTR + (g << 3)];
      acc[0][0] = __builtin_amdgcn_mfma_f32_32x32x16_bf16(aT[0], bT[0], acc[0][0], 0, 0, 0);
      acc[0][1] = __builtin_amdgcn_mfma_f32_32x32x16_bf16(aT[0], bT[1], acc[0][1], 0, 0, 0);
      acc[1][0] = __builtin_amdgcn_mfma_f32_32x32x16_bf16(aT[1], bT[0], acc[1][0], 0, 0, 0);
      acc[1][1] = __builtin_amdgcn_mfma_f32_32x32x16_bf16(aT[1], bT[1], acc[1][1], 0, 0, 0);
    }
    if (kt + 1 < nk) {
      __syncthreads();                  // all reads of buffer done (lgkm-only)
      // vmcnt waits here (covered by the compute phase above)
#pragma unroll
      for (int h = 0; h < 4; ++h) {
        *(bf16x8*)&lA[dOff[h]] = rA[h];
        *(bf16x8*)&lB[dOff[h]] = rB[h];
      }
      __syncthreads();                  // writes visible (lgkm-only)
      if (kt + 2 < nk) {
        const int ko = (kt + 2) << 6;
#pragma unroll
        for (int h = 0; h < 4; ++h) {
          rA[h] = *(const bf16x8*)(Abase + gOff[h] + ko);
          rB[h] = *(const bf16x8*)(Bbase + gOff[h] + ko);
        }
      }
    }
  }

  // C/D 32x32 (m74/m101): col = lane&31, row = (reg&3) + 8*(reg>>2) + 4*kh
  if (MODE == 0) {
    unsigned short* C = (unsigned short*)Cout;
#pragma unroll
    for (int mi = 0; mi < 2; ++mi)
#pragma unroll
      for (int reg = 0; reg < 16; ++reg) {
        int m = m0 + wm + mi * 32 + (reg & 3) + ((reg >> 2) << 3) + (kh << 2);
#pragma unroll
        for (int ni = 0; ni < 2; ++ni) {
          int n = n0 + wn + ni * 32 + r32;
          C[(size_t)m * N + n] = f2bf(acc[mi][ni][reg] * alpha);
        }
      }
  } else if (MODE == 1) {
    unsigned short* C = (unsigned short*)Cout;
#pragma unroll
    for (int mi = 0; mi < 2; ++mi)
#pragma unroll
      for (int reg = 0; reg < 16; ++reg) {
        int m = m0 + wm + mi * 32 + (reg & 3) + ((reg >> 2) << 3) + (kh << 2);
        float s = 0.f;
#pragma unroll
        for (int ni = 0; ni < 2; ++ni) {
          int n = n0 + wn + ni * 32 + r32;
          float p = __expf(acc[mi][ni][reg]);
          C[(size_t)m * N + n] = f2bf(p);
          s += p;
        }
        // reduce over the 32 lanes (r32) sharing this row
#pragma unroll
        for (int off = 1; off < 32; off <<= 1) s += __shfl_xor(s, off, 64);
        if (r32 == 0) atomicAdd(&rowsum[m], s);
      }
  } else {
    float* C = (float*)Cout;   // d_out fp32, zero-initialized; split-K partials
#pragma unroll
    for (int mi = 0; mi < 2; ++mi)
#pragma unroll
      for (int reg = 0; reg < 16; ++reg) {
        int m = m0 + wm + mi * 32 + (reg & 3) + ((reg >> 2) << 3) + (kh << 2);
        float inv = 1.0f / rowsum[m];
#pragma unroll
        for (int ni = 0; ni < 2; ++ni) {
          int n = n0 + wn + ni * 32 + r32;
          atomicAdd(&C[(size_t)m * N + n], acc[mi][ni][reg] * inv);
        }
      }
  }
}

extern "C" void kernel_launch(void* const* d_in, const int* in_sizes, int n_in,
                              void* d_out, int out_size, void* d_ws, size_t ws_size,
                              hipStream_t stream) {
  const float* x  = (const float*)d_in[0];
  const float* Wq = (const float*)d_in[1];
  const float* Wk = (const float*)d_in[2];
  const float* Wv = (const float*)d_in[3];

  char* ws = (char*)d_ws;
  unsigned short* xb     = (unsigned short*)(ws + 0);
  unsigned short* Qb     = (unsigned short*)(ws + 12582912);
  unsigned short* Kb     = (unsigned short*)(ws + 25165824);
  unsigned short* Vtb    = (unsigned short*)(ws + 37748736);
  unsigned short* wqb    = (unsigned short*)(ws + 50331648);
  unsigned short* wkb    = (unsigned short*)(ws + 51511296);
  unsigned short* wvb    = (unsigned short*)(ws + 52690944);
  float*          rowsum = (float*)(ws + 53870592);
  unsigned short* Pb     = (unsigned short*)(ws + 53903360);
  const size_t need = 53903360u + (size_t)SEQ * SEQ * 2u;
  if (ws_size < need) return;

  hipMemsetAsync(rowsum, 0, SEQ * sizeof(float), stream);
  hipMemsetAsync(d_out, 0, (size_t)out_size * sizeof(float), stream);

  convert_x<<<SEQ * DMODEL / 1024, 256, 0, stream>>>(x, xb, SEQ * DMODEL / 4);
  convert_w<<<dim3(DMODEL * DMODEL / 1024, 1, 3), 256, 0, stream>>>(
      Wq, Wk, Wv, wqb, wkb, wvb, DMODEL * DMODEL / 4);

  const float alpha_q = 0.03608439182435161f;  // 1/sqrt(768)
  dim3 blk(256);
  // grid.x = M-tiles, grid.y = N-tiles (XCD L2 locality)
  gemm_bt<0><<<dim3(SEQ / 128, DMODEL / 128, 2), blk, 0, stream>>>(
      xb, wqb, Qb, SEQ, DMODEL, DMODEL, alpha_q, nullptr, DMODEL,
      wkb, Kb, 1.0f);
  gemm_bt<0><<<dim3(DMODEL / 128, SEQ / 128, 1), blk, 0, stream>>>(
      wvb, xb, Vtb, DMODEL, SEQ, DMODEL, 1.0f, nullptr, DMODEL,
      nullptr, nullptr, 1.0f);
  gemm_bt<1><<<dim3(SEQ / 128, SEQ / 128, 1), blk, 0, stream>>>(
      Qb, Kb, Pb, SEQ, SEQ, DMODEL, 1.0f, rowsum, DMODEL,
      nullptr, nullptr, 1.0f);
  gemm_bt<2><<<dim3(SEQ / 128, DMODEL / 128, KSPLIT), blk, 0, stream>>>(
      Pb, Vtb, d_out, SEQ, DMODEL, SEQ, 1.0f, rowsum, SEQ / KSPLIT,
      nullptr, nullptr, 1.0f);
}